// Round 3
// baseline (476.213 us; speedup 1.0000x reference)
//
#include <hip/hip_runtime.h>
#include <math.h>

#define D_MODEL 1024
#define D_HEAD  64
#define SEQ     2048
#define BATCH   4
#define NROWS   (BATCH * SEQ)   // 8192

// ---------------------------------------------------------------------------
// Kernel 1: transpose W into WT[192][1024] so the projection can read W rows
// with wave-uniform (scalar) loads. cg = 0..63 -> Wq col, 64..127 -> Wk,
// 128..191 -> Wv.
// ---------------------------------------------------------------------------
__global__ __launch_bounds__(256) void wt_transpose(
    const float* __restrict__ Wq, const float* __restrict__ Wk,
    const float* __restrict__ Wv, float* __restrict__ WT)
{
    const int cg = blockIdx.x;          // 0..191
    const int c  = cg & 63;
    const float* W = (cg < 64) ? Wq : (cg < 128) ? Wk : Wv;
    const int t = threadIdx.x;
#pragma unroll
    for (int i = 0; i < 4; ++i) {
        int d = i * 256 + t;
        WT[(size_t)cg * D_MODEL + d] = W[(size_t)d * D_HEAD + c];
    }
}

// ---------------------------------------------------------------------------
// Kernel 2: QKV projection.  out[row][cg] = sum_d x[row][d] * WT[cg][d] + b
// grid = 256 blocks (128 row-blocks x 2 col-blocks), 256 threads = 4 waves.
// Each wave: 64 rows (lane == row) x 24 cols.  W read via uniform address
// (SGPR-resident) so the inner loop is pure v_fmac(vgpr, sgpr).
// x tile staged transposed in LDS: xs[kk][row-local], pad 65 (2-way = free).
// ---------------------------------------------------------------------------
__global__ __launch_bounds__(256) void qkv_proj(
    const float* __restrict__ x, const float* __restrict__ WT,
    const float* __restrict__ bq, const float* __restrict__ bk,
    const float* __restrict__ bv,
    float* __restrict__ q, float* __restrict__ k, float* __restrict__ v)
{
    __shared__ float xs[32][65];

    const int t    = threadIdx.x;
    const int lane = t & 63;
    const int wv   = __builtin_amdgcn_readfirstlane(t >> 6);  // wave id, scalar
    const int rowblk = blockIdx.x >> 1;
    const int colblk = blockIdx.x & 1;
    const int c0  = colblk * 96 + wv * 24;   // 24-col group, wave-uniform
    const int r0  = rowblk * 64;
    const int row = r0 + lane;

    float acc[24];
#pragma unroll
    for (int i = 0; i < 24; ++i) acc[i] = 0.f;

    const int srow = t >> 2;         // 0..63 (staging row)
    const int scol = (t & 3) * 8;    // 0,8,16,24 (staging col base)

    for (int k0 = 0; k0 < D_MODEL; k0 += 32) {
        __syncthreads();
        // stage x[r0+srow][k0+scol .. +7] -> xs[scol..+7][srow] (transposed)
        float4 a = *(const float4*)&x[(size_t)(r0 + srow) * D_MODEL + k0 + scol];
        float4 b = *(const float4*)&x[(size_t)(r0 + srow) * D_MODEL + k0 + scol + 4];
        xs[scol + 0][srow] = a.x; xs[scol + 1][srow] = a.y;
        xs[scol + 2][srow] = a.z; xs[scol + 3][srow] = a.w;
        xs[scol + 4][srow] = b.x; xs[scol + 5][srow] = b.y;
        xs[scol + 6][srow] = b.z; xs[scol + 7][srow] = b.w;
        __syncthreads();

        float xr[32];
#pragma unroll
        for (int kk = 0; kk < 32; ++kk) xr[kk] = xs[kk][lane];

#pragma unroll   // FULL unroll: acc[] must be compile-time indexed (no scratch)
        for (int c = 0; c < 24; ++c) {
            const float4* wp = (const float4*)(WT + (size_t)(c0 + c) * D_MODEL + k0);
#pragma unroll
            for (int i = 0; i < 8; ++i) {
                float4 w = wp[i];
                acc[c] += xr[i * 4 + 0] * w.x + xr[i * 4 + 1] * w.y +
                          xr[i * 4 + 2] * w.z + xr[i * 4 + 3] * w.w;
            }
        }
    }

    // bias + store (column writes; uncoalesced but only 6 MB total)
#pragma unroll
    for (int c = 0; c < 24; ++c) {
        int cg  = c0 + c;
        int mat = cg >> 6, cc = cg & 63;
        float bias = (mat == 0) ? bq[cc] : (mat == 1) ? bk[cc] : bv[cc];
        float* o   = (mat == 0) ? q : (mat == 1) ? k : v;
        o[(size_t)row * D_HEAD + cc] = acc[c] + bias;
    }
}

// ---------------------------------------------------------------------------
// Kernel 3: causal flash attention, f32.
// grid = (128 q-tiles, 4 batches), heavy tiles first (load balance).
// Block: 16 q-rows; thread (r = t>>4, g = t&15): 4 scores / 4 out cols.
// K/V tiles (64 keys) in LDS, pad 68 (16B-aligned rows, <=2-way conflicts).
// Online softmax is 16-lane shfl_xor; P goes through LDS within one wave
// (same-wave DS ordering -> no extra barrier needed).
// ---------------------------------------------------------------------------
__global__ __launch_bounds__(256) void attention(
    const float* __restrict__ q, const float* __restrict__ k,
    const float* __restrict__ v, float* __restrict__ out)
{
    __shared__ float ks[64][68];
    __shared__ float vs[64][68];
    __shared__ float ps[16][68];

    const int t  = threadIdx.x;
    const int b  = blockIdx.y;
    const int qt = (int)gridDim.x - 1 - (int)blockIdx.x;   // heavy first
    const int rbase = qt * 16;
    const int r = t >> 4;        // 0..15 (q row in tile)
    const int g = t & 15;        // 0..15 (key/col group)
    const int grow = rbase + r;  // global q row

    // q row -> registers, pre-scaled by 1/sqrt(64)
    float qr[64];
    {
        const float* qp = &q[((size_t)b * SEQ + grow) * D_HEAD];
#pragma unroll
        for (int i = 0; i < 16; ++i) {
            float4 a = *(const float4*)&qp[i * 4];
            qr[i * 4 + 0] = a.x * 0.125f; qr[i * 4 + 1] = a.y * 0.125f;
            qr[i * 4 + 2] = a.z * 0.125f; qr[i * 4 + 3] = a.w * 0.125f;
        }
    }

    float m = -1e30f, l = 0.f;
    float o0 = 0.f, o1 = 0.f, o2 = 0.f, o3 = 0.f;

    const int nkt   = rbase / 64 + 1;
    const int srow  = t >> 2;          // 0..63 (staging row)
    const int scol0 = (t & 3) * 4;     // 0,4,8,12 (contiguous 64B per 4 lanes)

    for (int kt = 0; kt < nkt; ++kt) {
        __syncthreads();
        {
            const float* kp = &k[((size_t)b * SEQ + kt * 64 + srow) * D_HEAD];
            const float* vp = &v[((size_t)b * SEQ + kt * 64 + srow) * D_HEAD];
#pragma unroll
            for (int i = 0; i < 4; ++i) {
                *(float4*)&ks[srow][scol0 + i * 16] = *(const float4*)&kp[scol0 + i * 16];
                *(float4*)&vs[srow][scol0 + i * 16] = *(const float4*)&vp[scol0 + i * 16];
            }
        }
        __syncthreads();

        // scores: 4 keys per thread (kk = g + 16j)
        float s[4];
#pragma unroll
        for (int j = 0; j < 4; ++j) {
            int kk = g + 16 * j;
            float acc = 0.f;
#pragma unroll
            for (int d4 = 0; d4 < 16; ++d4) {
                float4 kv = *(const float4*)&ks[kk][d4 * 4];
                acc += qr[d4 * 4 + 0] * kv.x + qr[d4 * 4 + 1] * kv.y +
                       qr[d4 * 4 + 2] * kv.z + qr[d4 * 4 + 3] * kv.w;
            }
            int key = kt * 64 + kk;
            s[j] = (key <= grow) ? acc : -1e30f;
        }

        // online softmax (16-lane group owns one row)
        float tm = fmaxf(fmaxf(s[0], s[1]), fmaxf(s[2], s[3]));
#pragma unroll
        for (int off = 1; off < 16; off <<= 1) tm = fmaxf(tm, __shfl_xor(tm, off));
        float mn  = fmaxf(m, tm);
        float fac = __expf(m - mn);
        float p[4], ts = 0.f;
#pragma unroll
        for (int j = 0; j < 4; ++j) { p[j] = __expf(s[j] - mn); ts += p[j]; }
#pragma unroll
        for (int off = 1; off < 16; off <<= 1) ts += __shfl_xor(ts, off);
        l = l * fac + ts;
        o0 *= fac; o1 *= fac; o2 *= fac; o3 *= fac;
        m = mn;

#pragma unroll
        for (int j = 0; j < 4; ++j) ps[r][g + 16 * j] = p[j];
        // P written+read by the same wave's 16-lane group: DS ops are in-order
        // within a wave, no barrier needed.

        // PV: out cols c = g*4 .. g*4+3
#pragma unroll
        for (int i = 0; i < 16; ++i) {
            float4 pp = *(const float4*)&ps[r][i * 4];
            float4 v0 = *(const float4*)&vs[i * 4 + 0][g * 4];
            float4 v1 = *(const float4*)&vs[i * 4 + 1][g * 4];
            float4 v2 = *(const float4*)&vs[i * 4 + 2][g * 4];
            float4 v3 = *(const float4*)&vs[i * 4 + 3][g * 4];
            o0 += pp.x * v0.x + pp.y * v1.x + pp.z * v2.x + pp.w * v3.x;
            o1 += pp.x * v0.y + pp.y * v1.y + pp.z * v2.y + pp.w * v3.y;
            o2 += pp.x * v0.z + pp.y * v1.z + pp.z * v2.z + pp.w * v3.z;
            o3 += pp.x * v0.w + pp.y * v1.w + pp.z * v2.w + pp.w * v3.w;
        }
    }

    float inv = 1.f / l;
    float4 res = make_float4(o0 * inv, o1 * inv, o2 * inv, o3 * inv);
    *(float4*)&out[((size_t)b * SEQ + grow) * D_HEAD + g * 4] = res;
}

// ---------------------------------------------------------------------------
extern "C" void kernel_launch(void* const* d_in, const int* in_sizes, int n_in,
                              void* d_out, int out_size, void* d_ws, size_t ws_size,
                              hipStream_t stream)
{
    (void)in_sizes; (void)n_in; (void)out_size; (void)ws_size;

    const float* x  = (const float*)d_in[0];
    const float* Wq = (const float*)d_in[1];
    const float* bq = (const float*)d_in[2];
    const float* Wk = (const float*)d_in[3];
    const float* bk = (const float*)d_in[4];
    const float* Wv = (const float*)d_in[5];
    const float* bv = (const float*)d_in[6];
    float* out = (float*)d_out;

    // workspace layout (floats): WT[192*1024] | q | k | v  (7.1 MB total)
    float* WT = (float*)d_ws;
    float* q  = WT + 192 * D_MODEL;
    float* k  = q + (size_t)NROWS * D_HEAD;
    float* v  = k + (size_t)NROWS * D_HEAD;

    wt_transpose<<<192, 256, 0, stream>>>(Wq, Wk, Wv, WT);
    qkv_proj<<<256, 256, 0, stream>>>(x, WT, bq, bk, bv, q, k, v);
    attention<<<dim3(128, BATCH), 256, 0, stream>>>(q, k, v, out);
}

// Round 5
// 180.156 us; speedup vs baseline: 2.6433x; 2.6433x over previous
//
#include <hip/hip_runtime.h>
#include <math.h>

#define D_MODEL 1024
#define SEQ     2048
#define BATCH   4
#define NROWS   (BATCH * SEQ)   // 8192

typedef short bf16x8 __attribute__((ext_vector_type(8)));
typedef float f32x4  __attribute__((ext_vector_type(4)));

// f32 -> bf16 round-to-nearest-even (inputs are well-behaved, no NaN care)
static __device__ __forceinline__ unsigned short f2bf(float f) {
    unsigned int x = __float_as_uint(f);
    x += 0x7FFFu + ((x >> 16) & 1u);
    return (unsigned short)(x >> 16);
}

// ---------------------------------------------------------------------------
// Kernel 1: pack W (f32, [1024][64] k-major, x3) into Wb[192][1024] bf16
// (col-major rows so GEMM B-operand reads are contiguous along K).
// ---------------------------------------------------------------------------
__global__ __launch_bounds__(256) void w_pack(
    const float* __restrict__ Wq, const float* __restrict__ Wk,
    const float* __restrict__ Wv, unsigned short* __restrict__ Wb)
{
    const int cg = blockIdx.x;            // 0..191
    const int cc = cg & 63;
    const float* W = (cg < 64) ? Wq : (cg < 128) ? Wk : Wv;
#pragma unroll
    for (int i = 0; i < 4; ++i) {
        int k = i * 256 + threadIdx.x;
        Wb[(size_t)cg * D_MODEL + k] = f2bf(W[(size_t)k * 64 + cc]);
    }
}

// ---------------------------------------------------------------------------
// Kernel 2: QKV projection via MFMA.  C[8192][192] = x[8192][1024] @ Wb^T.
// BM=32, BN=192, BK=64; 256 blocks x 4 waves (each wave: 32 rows x 48 cols).
// A reg-staged (f32->bf16 cvt in flight), B reg-staged from Wb.
// LDS rows padded to 72 bf16 (144B) -> uniform bank coverage on b128 ops.
// Epilogue: qb (x0.125 pre-scale), kb, and V stored TRANSPOSED (Vt[b][d][seq]).
// ---------------------------------------------------------------------------
__global__ __launch_bounds__(256) void qkv_proj_mfma(
    const float* __restrict__ x, const unsigned short* __restrict__ Wb,
    const float* __restrict__ bq, const float* __restrict__ bk,
    const float* __restrict__ bv,
    unsigned short* __restrict__ qb, unsigned short* __restrict__ kb,
    unsigned short* __restrict__ Vt)
{
    __shared__ unsigned short A_lds[32 * 72];
    __shared__ unsigned short B_lds[192 * 72];

    const int tid  = threadIdx.x;
    const int lane = tid & 63;
    const int wn   = tid >> 6;        // wave id -> col strip
    const int lg   = lane >> 4;       // 0..3
    const int lc   = lane & 15;       // 0..15
    const int m0   = blockIdx.x * 32;

    f32x4 acc[2][3];
#pragma unroll
    for (int mf = 0; mf < 2; ++mf)
#pragma unroll
        for (int nf = 0; nf < 3; ++nf) acc[mf][nf] = (f32x4){0.f, 0.f, 0.f, 0.f};

    const int arow = tid >> 3, asp = tid & 7;     // A: row 0..31, slot 0..7
    float4 areg0, areg1;
    uint4  breg[6];

    // prologue: load K-iter 0
    {
        const float* ap = &x[(size_t)(m0 + arow) * D_MODEL + asp * 8];
        areg0 = *(const float4*)ap;
        areg1 = *(const float4*)(ap + 4);
#pragma unroll
        for (int i = 0; i < 6; ++i) {
            int c = tid + 256 * i, brow = c >> 3, bsp = c & 7;
            breg[i] = *(const uint4*)&Wb[(size_t)brow * D_MODEL + bsp * 8];
        }
    }

    for (int it = 0; it < 16; ++it) {
        __syncthreads();   // everyone done reading LDS from previous iter
        // store staged regs -> LDS
        {
            unsigned int a0 = f2bf(areg0.x) | ((unsigned)f2bf(areg0.y) << 16);
            unsigned int a1 = f2bf(areg0.z) | ((unsigned)f2bf(areg0.w) << 16);
            unsigned int a2 = f2bf(areg1.x) | ((unsigned)f2bf(areg1.y) << 16);
            unsigned int a3 = f2bf(areg1.z) | ((unsigned)f2bf(areg1.w) << 16);
            *(uint4*)&A_lds[arow * 72 + asp * 8] = make_uint4(a0, a1, a2, a3);
#pragma unroll
            for (int i = 0; i < 6; ++i) {
                int c = tid + 256 * i, brow = c >> 3, bsp = c & 7;
                *(uint4*)&B_lds[brow * 72 + bsp * 8] = breg[i];
            }
        }
        // issue next-iter loads (latency hides under compute below)
        if (it < 15) {
            int k0 = (it + 1) * 64;
            const float* ap = &x[(size_t)(m0 + arow) * D_MODEL + k0 + asp * 8];
            areg0 = *(const float4*)ap;
            areg1 = *(const float4*)(ap + 4);
#pragma unroll
            for (int i = 0; i < 6; ++i) {
                int c = tid + 256 * i, brow = c >> 3, bsp = c & 7;
                breg[i] = *(const uint4*)&Wb[(size_t)brow * D_MODEL + k0 + bsp * 8];
            }
        }
        __syncthreads();   // LDS tile ready
#pragma unroll
        for (int kk = 0; kk < 2; ++kk) {
            bf16x8 af[2], bfr[3];
#pragma unroll
            for (int mf = 0; mf < 2; ++mf)
                af[mf] = *(const bf16x8*)&A_lds[(mf * 16 + lc) * 72 + kk * 32 + lg * 8];
#pragma unroll
            for (int nf = 0; nf < 3; ++nf)
                bfr[nf] = *(const bf16x8*)&B_lds[(wn * 48 + nf * 16 + lc) * 72 + kk * 32 + lg * 8];
#pragma unroll
            for (int mf = 0; mf < 2; ++mf)
#pragma unroll
                for (int nf = 0; nf < 3; ++nf)
                    acc[mf][nf] = __builtin_amdgcn_mfma_f32_16x16x32_bf16(
                        af[mf], bfr[nf], acc[mf][nf], 0, 0, 0);
        }
    }

    // epilogue: D-frag mapping col = lane&15, row = (lane>>4)*4 + r
#pragma unroll
    for (int mf = 0; mf < 2; ++mf) {
#pragma unroll
        for (int nf = 0; nf < 3; ++nf) {
            int col = wn * 48 + nf * 16 + lc;
            int mat = col >> 6, cc = col & 63;
            int grow0 = m0 + mf * 16 + lg * 4;
            if (mat == 0) {
                float bias = bq[cc];
#pragma unroll
                for (int r = 0; r < 4; ++r)
                    qb[(size_t)(grow0 + r) * 64 + cc] = f2bf((acc[mf][nf][r] + bias) * 0.125f);
            } else if (mat == 1) {
                float bias = bk[cc];
#pragma unroll
                for (int r = 0; r < 4; ++r)
                    kb[(size_t)(grow0 + r) * 64 + cc] = f2bf(acc[mf][nf][r] + bias);
            } else {
                float bias = bv[cc];
                int bb = grow0 >> 11, seq = grow0 & 2047;
                ushort4 pk;
                pk.x = f2bf(acc[mf][nf][0] + bias);
                pk.y = f2bf(acc[mf][nf][1] + bias);
                pk.z = f2bf(acc[mf][nf][2] + bias);
                pk.w = f2bf(acc[mf][nf][3] + bias);
                *(ushort4*)&Vt[((size_t)bb * 64 + cc) * SEQ + seq] = pk;
            }
        }
    }
}

// ---------------------------------------------------------------------------
// Kernel 3: causal flash attention partials, MFMA bf16.
// Grid (qt 0..63, chunk 0..3, batch 0..3); chunk = 512 keys = 8 tiles of 64.
// Block = 128 thr = 2 waves; wave w owns q-rows qt*32 + w*16 .. +15.
// Online softmax per 16-lane group on the MFMA D-layout; P relayout through
// padded LDS (same-wave write->read, compiler-ordered lgkmcnt, no barrier).
// Partial (m, l, O) per (b, qt, chunk) written to workspace.
// ---------------------------------------------------------------------------
__global__ __launch_bounds__(128) void attn_partial(
    const unsigned short* __restrict__ qb, const unsigned short* __restrict__ kb,
    const unsigned short* __restrict__ Vt,
    float* __restrict__ O_part, float* __restrict__ ml)
{
    __shared__ unsigned short K_lds[64 * 72];
    __shared__ unsigned short V_lds[64 * 72];
    __shared__ unsigned short P_lds[2 * 16 * 72];

    const int qt  = blockIdx.x;
    const int ch  = blockIdx.y;
    const int b   = blockIdx.z;
    const int tid = threadIdx.x;
    const int w    = tid >> 6;
    const int lane = tid & 63;
    const int lg   = lane >> 4, lc = lane & 15;

    const int qmax = qt * 32 + 31;
    int nt = ((qmax - ch * 512) >> 6) + 1;    // arithmetic shift = floor div
    if (nt > 8) nt = 8;
    if (nt <= 0) return;                      // block-uniform exit

    // Q fragments (A-layout: row = lane&15, k = (lane>>4)*8 + j, dk halves)
    const size_t qrow = (size_t)(b * SEQ + qt * 32 + w * 16 + lc);
    bf16x8 qf0 = *(const bf16x8*)&qb[qrow * 64 + lg * 8];
    bf16x8 qf1 = *(const bf16x8*)&qb[qrow * 64 + 32 + lg * 8];

    f32x4 O[4];
#pragma unroll
    for (int df = 0; df < 4; ++df) O[df] = (f32x4){0.f, 0.f, 0.f, 0.f};
    float m[4] = {-1e30f, -1e30f, -1e30f, -1e30f};
    float l[4] = {0.f, 0.f, 0.f, 0.f};

    uint4 kreg[4], vreg[4];
    // prologue: load tile 0
    {
        int kb0 = ch * 512;
#pragma unroll
        for (int i = 0; i < 4; ++i) {
            int c = i * 128 + tid, kr = c >> 3, sl = c & 7;
            kreg[i] = *(const uint4*)&kb[((size_t)(b * SEQ + kb0 + kr)) * 64 + sl * 8];
            vreg[i] = *(const uint4*)&Vt[((size_t)(b * 64 + kr)) * SEQ + kb0 + sl * 8];
        }
    }

    const int rowbase = qt * 32 + w * 16 + lg * 4;

    for (int t = 0; t < nt; ++t) {
        __syncthreads();   // all waves done reading previous tile
#pragma unroll
        for (int i = 0; i < 4; ++i) {
            int c = i * 128 + tid, kr = c >> 3, sl = c & 7;
            *(uint4*)&K_lds[kr * 72 + sl * 8] = kreg[i];
            *(uint4*)&V_lds[kr * 72 + sl * 8] = vreg[i];
        }
        if (t + 1 < nt) {                     // issue next-tile loads early
            int kb0n = ch * 512 + (t + 1) * 64;
#pragma unroll
            for (int i = 0; i < 4; ++i) {
                int c = i * 128 + tid, kr = c >> 3, sl = c & 7;
                kreg[i] = *(const uint4*)&kb[((size_t)(b * SEQ + kb0n + kr)) * 64 + sl * 8];
                vreg[i] = *(const uint4*)&Vt[((size_t)(b * 64 + kr)) * SEQ + kb0n + sl * 8];
            }
        }
        __syncthreads();   // tile ready

        const int kb0 = ch * 512 + t * 64;

        // QK^T: S[16 q x 64 keys] as 4 D-frags
        f32x4 s[4];
#pragma unroll
        for (int kf = 0; kf < 4; ++kf) s[kf] = (f32x4){0.f, 0.f, 0.f, 0.f};
#pragma unroll
        for (int kf = 0; kf < 4; ++kf) {
            bf16x8 k0 = *(const bf16x8*)&K_lds[(kf * 16 + lc) * 72 + lg * 8];
            bf16x8 k1 = *(const bf16x8*)&K_lds[(kf * 16 + lc) * 72 + 32 + lg * 8];
            s[kf] = __builtin_amdgcn_mfma_f32_16x16x32_bf16(qf0, k0, s[kf], 0, 0, 0);
            s[kf] = __builtin_amdgcn_mfma_f32_16x16x32_bf16(qf1, k1, s[kf], 0, 0, 0);
        }

        // online softmax; D-layout: key = kf*16 + (lane&15), row = rowbase + r
#pragma unroll
        for (int r = 0; r < 4; ++r) {
            float tm = -1e30f;
#pragma unroll
            for (int kf = 0; kf < 4; ++kf) {
                float sv = s[kf][r];
                if (kb0 + kf * 16 + lc > rowbase + r) sv = -1e30f;
                s[kf][r] = sv;
                tm = fmaxf(tm, sv);
            }
            tm = fmaxf(tm, __shfl_xor(tm, 1));
            tm = fmaxf(tm, __shfl_xor(tm, 2));
            tm = fmaxf(tm, __shfl_xor(tm, 4));
            tm = fmaxf(tm, __shfl_xor(tm, 8));
            float mn  = fmaxf(m[r], tm);
            float fac = __expf(m[r] - mn);
            float ts  = 0.f;
#pragma unroll
            for (int kf = 0; kf < 4; ++kf) {
                float p = __expf(s[kf][r] - mn);
                ts += p;
                P_lds[w * 1152 + (lg * 4 + r) * 72 + kf * 16 + lc] = f2bf(p);
            }
            ts += __shfl_xor(ts, 1);
            ts += __shfl_xor(ts, 2);
            ts += __shfl_xor(ts, 4);
            ts += __shfl_xor(ts, 8);
            l[r] = l[r] * fac + ts;
            m[r] = mn;
            O[0][r] *= fac; O[1][r] *= fac; O[2][r] *= fac; O[3][r] *= fac;
        }

        // PV: O[16 q x 64 d] += P[16 x 64] @ V[64 x 64]
        bf16x8 pf0 = *(const bf16x8*)&P_lds[w * 1152 + lc * 72 + lg * 8];
        bf16x8 pf1 = *(const bf16x8*)&P_lds[w * 1152 + lc * 72 + 32 + lg * 8];
#pragma unroll
        for (int df = 0; df < 4; ++df) {
            bf16x8 v0 = *(const bf16x8*)&V_lds[(df * 16 + lc) * 72 + lg * 8];
            bf16x8 v1 = *(const bf16x8*)&V_lds[(df * 16 + lc) * 72 + 32 + lg * 8];
            O[df] = __builtin_amdgcn_mfma_f32_16x16x32_bf16(pf0, v0, O[df], 0, 0, 0);
            O[df] = __builtin_amdgcn_mfma_f32_16x16x32_bf16(pf1, v1, O[df], 0, 0, 0);
        }
    }

    // write partials
    const int slot = (b * 64 + qt) * 4 + ch;
    float* Op = O_part + (size_t)slot * 2048;
#pragma unroll
    for (int df = 0; df < 4; ++df)
#pragma unroll
        for (int r = 0; r < 4; ++r)
            Op[(w * 16 + lg * 4 + r) * 64 + df * 16 + lc] = O[df][r];
    if (lc == 0) {
#pragma unroll
        for (int r = 0; r < 4; ++r) {
            ml[slot * 64 + w * 16 + lg * 4 + r]      = m[r];
            ml[slot * 64 + 32 + w * 16 + lg * 4 + r] = l[r];
        }
    }
}

// ---------------------------------------------------------------------------
// Kernel 4: merge chunk partials -> final output (f32).
// ---------------------------------------------------------------------------
__global__ __launch_bounds__(256) void attn_merge(
    const float* __restrict__ O_part, const float* __restrict__ ml,
    float* __restrict__ out)
{
    int idx = blockIdx.x * 256 + threadIdx.x;   // 262144 threads, 2 f32 each
    int row = idx >> 5;
    int d0  = (idx & 31) * 2;
    int b = row >> 11, seq = row & 2047;
    int qt = seq >> 5, rl = seq & 31;
    int nc = (qt >> 4) + 1;
    int sbase = (b * 64 + qt) * 4;

    float M = -1e30f;
    for (int c = 0; c < nc; ++c) M = fmaxf(M, ml[(sbase + c) * 64 + rl]);
    float L = 0.f, o0 = 0.f, o1 = 0.f;
    for (int c = 0; c < nc; ++c) {
        float e = __expf(ml[(sbase + c) * 64 + rl] - M);
        L += e * ml[(sbase + c) * 64 + 32 + rl];
        const float* Op = O_part + (size_t)(sbase + c) * 2048 + rl * 64 + d0;
        o0 += e * Op[0];
        o1 += e * Op[1];
    }
    float inv = 1.f / L;
    *(float2*)&out[(size_t)row * 64 + d0] = make_float2(o0 * inv, o1 * inv);
}

// ---------------------------------------------------------------------------
extern "C" void kernel_launch(void* const* d_in, const int* in_sizes, int n_in,
                              void* d_out, int out_size, void* d_ws, size_t ws_size,
                              hipStream_t stream)
{
    (void)in_sizes; (void)n_in; (void)out_size; (void)ws_size;

    const float* x  = (const float*)d_in[0];
    const float* Wq = (const float*)d_in[1];
    const float* bq = (const float*)d_in[2];
    const float* Wk = (const float*)d_in[3];
    const float* bk = (const float*)d_in[4];
    const float* Wv = (const float*)d_in[5];
    const float* bv = (const float*)d_in[6];
    float* out = (float*)d_out;

    // workspace layout (bytes, all 16B-aligned):
    // Wb: 192*1024*2 = 393216       qb/kb/Vt: 8192*64*2 = 1048576 each
    // ml: 1024*64*4 = 262144        O_part: 1024*2048*4 = 8388608
    char* ws = (char*)d_ws;
    unsigned short* Wb = (unsigned short*)(ws);
    unsigned short* qb = (unsigned short*)(ws + 393216);
    unsigned short* kb = (unsigned short*)(ws + 393216 + 1048576);
    unsigned short* Vt = (unsigned short*)(ws + 393216 + 2 * 1048576);
    float*          ml = (float*)(ws + 393216 + 3 * 1048576);
    float*      O_part = (float*)(ws + 393216 + 3 * 1048576 + 262144);

    w_pack<<<192, 256, 0, stream>>>(Wq, Wk, Wv, Wb);
    qkv_proj_mfma<<<256, 256, 0, stream>>>(x, Wb, bq, bk, bv, qb, kb, Vt);
    attn_partial<<<dim3(64, 4, 4), 128, 0, stream>>>(qb, kb, Vt, O_part, ml);
    attn_merge<<<1024, 256, 0, stream>>>(O_part, ml, out);
}